// Round 18
// baseline (133.530 us; speedup 1.0000x reference)
//
#include <hip/hip_runtime.h>

#define H   128
#define P   32             // points per block
#define NT  512            // 8 waves: wave = jquad*2 + phalf

typedef _Float16 v8h __attribute__((ext_vector_type(8)));
typedef __fp16   h2  __attribute__((ext_vector_type(2)));   // cvt_pkrtz return type
typedef float    v4f __attribute__((ext_vector_type(4)));
typedef float    v2f __attribute__((ext_vector_type(2)));   // -> VOP3P v_pk_*_f32

union PK4 { h2 h[4]; uint4 u; };       // 8 f16 = 16 B
union PK2 { h2 h[2]; uint2 u; };       // 4 f16 = 8 B

// State plane layout: [pl][p][k], 128 f16 per row, XOR-octet swizzle; returns
// f16 index of octet o of row p.
__device__ __forceinline__ int soct(int pl, int p, int o) {
    return ((pl * P + p) * 16 + (o ^ (p & 15))) << 3;
}

// Async global->LDS DMA, 16 B per lane. LDS dest = wave-uniform base +
// lane*16 (m97/m104 semantics) — our staging is wave-linear, which matches.
__device__ __forceinline__ void ldsdma16(const _Float16* g, _Float16* l) {
    __builtin_amdgcn_global_load_lds(
        (const __attribute__((address_space(1))) void*)g,
        (__attribute__((address_space(3))) void*)l, 16, 0, 0);
}

// Prepass (2nd dispatch is free — R10/R11 A/B): Wt in LDS physical order
// ws[l][oct][j][8], oct = k>>3. Main-kernel staging = pure linear DMA.
__global__ void wt_convert(const float* __restrict__ W1,
                           const float* __restrict__ W2,
                           _Float16* __restrict__ ws) {
    const int t = blockIdx.x * 64 + threadIdx.x;   // 0..16383 (u32 units)
    const int l = t >> 13;
    const int r = t & 8191;
    const int oct = r >> 9;
    const int rem = r & 511;
    const int j  = rem >> 2;
    const int wp = rem & 3;
    const int k  = oct * 8 + 2 * wp;
    const float* __restrict__ W = l ? W2 : W1;
    const float a = W[k * H + j];
    const float b = W[(k + 1) * H + j];
    union { h2 h; unsigned u; } q;
    q.h = __builtin_amdgcn_cvt_pkrtz(a, b);
    ((unsigned*)ws)[t] = q.u;
}

// Packed-pair tanh + derivatives: exp/rcp scalar, fma chain packed (VOP3P).
__device__ __forceinline__ v2f tanh_d2_p(v2f z, v2f& g1, v2f& g2) {
    v2f r;
    r.x = __builtin_amdgcn_rcpf(__expf(2.f * z.x) + 1.f);
    r.y = __builtin_amdgcn_rcpf(__expf(2.f * z.y) + 1.f);
    const v2f a = -2.f * r + 1.f;                  // e=inf -> r=0 -> a=1
    g1 = 1.f - a * a;
    g2 = -2.f * (a * g1);
    return a;
}

// R18 = R17 + async DMA W-staging: layer-1 DMA issued at entry (overlaps L0),
// layer-2 DMA issued right after barrier 2 (overlaps the combine phase), no
// VGPR round-trip, no ds_write issue slots. Barriers drain vmcnt (m97), so
// each wave's own DMA is complete at the next __syncthreads.
// GEMM: A = Wt (m=j, LDS), B = state (n=p, LDS); C row j = quad*4+r, col p = l15.
__global__ __launch_bounds__(NT, 4)
void pinn_hess_mfma(const float* __restrict__ X,
                    const float* __restrict__ W0, const float* __restrict__ b0,
                    const _Float16* __restrict__ Wt,
                    const float* __restrict__ b1, const float* __restrict__ b2,
                    const float* __restrict__ W3,
                    float* __restrict__ out, int N)
{
    __shared__ _Float16 sS[6 * P * H];        // 49152 B, swizzled state planes
    __shared__ _Float16 sW[16 * H * 8];       // 32768 B, one full W layer (oct-planes)

    const int tid   = threadIdx.x;
    const int wave  = tid >> 6;               // 0..7
    const int phalf = wave & 1;               // p-half: cols phalf*16..+16
    const int jquad = wave >> 1;              // j range jquad*32..+32
    const int lane  = tid & 63;
    const int quad  = lane >> 4;
    const int l15   = lane & 15;
    const int pbase = blockIdx.x * P;
    const int pmy   = phalf * 16 + l15;       // this lane's point row (GEMM n)
    const int wb    = wave * 64;              // wave-uniform lane-0 offset

    // issue layer-1 W staging DMA (completes by barrier 1, hidden behind L0)
    #pragma unroll
    for (int i = 0; i < 4; ++i)
        ldsdma16(Wt + (i * NT + tid) * 8, sW + (i * NT + wb) * 8);

    // ---------------- layer 0 (input dim 2, analytic); 512 tasks = 1/thread --
    {
        const int p = tid >> 4, o = tid & 15;
        const float x = X[2 * (pbase + p)];
        const float y = X[2 * (pbase + p) + 1];
        float wxv[8], wyv[8], bv[8];
        *(float4*)&wxv[0] = *(const float4*)&W0[o * 8];
        *(float4*)&wxv[4] = *(const float4*)&W0[o * 8 + 4];
        *(float4*)&wyv[0] = *(const float4*)&W0[H + o * 8];
        *(float4*)&wyv[4] = *(const float4*)&W0[H + o * 8 + 4];
        *(float4*)&bv[0]  = *(const float4*)&b0[o * 8];
        *(float4*)&bv[4]  = *(const float4*)&b0[o * 8 + 4];
        PK4 q[6];
        #pragma unroll
        for (int hp = 0; hp < 4; ++hp) {       // j-pairs, packed math
            const v2f wx = {wxv[2*hp], wxv[2*hp+1]};
            const v2f wy = {wyv[2*hp], wyv[2*hp+1]};
            const v2f bb = {bv[2*hp],  bv[2*hp+1]};
            v2f g1, g2;
            const v2f a = tanh_d2_p(x * wx + y * wy + bb, g1, g2);
            const v2f gx = g2 * wx;
            const v2f r0 = a,        r1 = g1 * wx,  r2 = g1 * wy;
            const v2f r3 = gx * wx,  r4 = gx * wy,  r5 = (g2 * wy) * wy;
            q[0].h[hp] = __builtin_amdgcn_cvt_pkrtz(r0.x, r0.y);
            q[1].h[hp] = __builtin_amdgcn_cvt_pkrtz(r1.x, r1.y);
            q[2].h[hp] = __builtin_amdgcn_cvt_pkrtz(r2.x, r2.y);
            q[3].h[hp] = __builtin_amdgcn_cvt_pkrtz(r3.x, r3.y);
            q[4].h[hp] = __builtin_amdgcn_cvt_pkrtz(r4.x, r4.y);
            q[5].h[hp] = __builtin_amdgcn_cvt_pkrtz(r5.x, r5.y);
        }
        #pragma unroll
        for (int pl = 0; pl < 6; ++pl)
            *(uint4*)&sS[soct(pl, p, o)] = q[pl].u;
    }
    __syncthreads();   // (1) DMA drained + sS visible

    v4f C[6][2];
    auto kloop = [&]() {
        #pragma unroll
        for (int pl = 0; pl < 6; ++pl) { C[pl][0] = (v4f){0,0,0,0}; C[pl][1] = (v4f){0,0,0,0}; }
        #pragma unroll
        for (int kc = 0; kc < 4; ++kc) {
            const int oct = kc * 4 + quad;
            const v8h A0 = *(const v8h*)&sW[(oct * H + jquad * 32 + l15)      * 8];
            const v8h A1 = *(const v8h*)&sW[(oct * H + jquad * 32 + 16 + l15) * 8];
            #pragma unroll
            for (int pl = 0; pl < 6; ++pl) {
                const v8h B = *(const v8h*)&sS[soct(pl, pmy, oct)];
                C[pl][0] = __builtin_amdgcn_mfma_f32_16x16x32_f16(A0, B, C[pl][0], 0, 0, 0);
                C[pl][1] = __builtin_amdgcn_mfma_f32_16x16x32_f16(A1, B, C[pl][1], 0, 0, 0);
            }
        }
    };

    // ---------------- layer 1 ----------------
    kloop();
    __syncthreads();   // (2) K-loop reads of sW/sS done

    // issue layer-2 W staging DMA (overlaps the combine VALU phase below)
    #pragma unroll
    for (int i = 0; i < 4; ++i)
        ldsdma16(Wt + (2048 + i * NT + tid) * 8, sW + (i * NT + wb) * 8);

    // packed in-register tanh chain rule; b64 vector writeback
    #pragma unroll
    for (int mt = 0; mt < 2; ++mt) {
        const int j0 = jquad * 32 + mt * 16 + quad * 4;
        const float4 bv = *(const float4*)&b1[j0];
        PK2 q[6];
        #pragma unroll
        for (int hp = 0; hp < 2; ++hp) {   // r-pairs (0,1) and (2,3)
            const v2f zb = hp ? (v2f){C[0][mt][2], C[0][mt][3]}
                              : (v2f){C[0][mt][0], C[0][mt][1]};
            const v2f bb = hp ? (v2f){bv.z, bv.w} : (v2f){bv.x, bv.y};
            const v2f tx = hp ? (v2f){C[1][mt][2], C[1][mt][3]}
                              : (v2f){C[1][mt][0], C[1][mt][1]};
            const v2f ty = hp ? (v2f){C[2][mt][2], C[2][mt][3]}
                              : (v2f){C[2][mt][0], C[2][mt][1]};
            const v2f cx = hp ? (v2f){C[3][mt][2], C[3][mt][3]}
                              : (v2f){C[3][mt][0], C[3][mt][1]};
            const v2f cm = hp ? (v2f){C[4][mt][2], C[4][mt][3]}
                              : (v2f){C[4][mt][0], C[4][mt][1]};
            const v2f cy = hp ? (v2f){C[5][mt][2], C[5][mt][3]}
                              : (v2f){C[5][mt][0], C[5][mt][1]};
            v2f g1, g2;
            const v2f a  = tanh_d2_p(zb + bb, g1, g2);
            const v2f gx = g2 * tx;
            const v2f s0 = a,        s1 = g1 * tx,          s2 = g1 * ty;
            const v2f s3 = gx * tx + g1 * cx;
            const v2f s4 = gx * ty + g1 * cm;
            const v2f s5 = (g2 * ty) * ty + g1 * cy;
            q[0].h[hp] = __builtin_amdgcn_cvt_pkrtz(s0.x, s0.y);
            q[1].h[hp] = __builtin_amdgcn_cvt_pkrtz(s1.x, s1.y);
            q[2].h[hp] = __builtin_amdgcn_cvt_pkrtz(s2.x, s2.y);
            q[3].h[hp] = __builtin_amdgcn_cvt_pkrtz(s3.x, s3.y);
            q[4].h[hp] = __builtin_amdgcn_cvt_pkrtz(s4.x, s4.y);
            q[5].h[hp] = __builtin_amdgcn_cvt_pkrtz(s5.x, s5.y);
        }
        const int ob = j0 >> 3;            // octet of j0
        const int ho = (quad & 1) * 4;     // half-offset within octet
        #pragma unroll
        for (int pl = 0; pl < 6; ++pl)
            *(uint2*)&sS[soct(pl, pmy, ob) + ho] = q[pl].u;
    }
    __syncthreads();   // (3) new state + layer-2 DMA drained

    // ---------------- layer 2 ----------------
    kloop();
    __syncthreads();   // (4) sW reads done -> reusable as sRed

    // final combine + W3 dot, packed; reduce j over quads then jquads
    {
        v2f axx = {0.f, 0.f}, axy = {0.f, 0.f}, ayy = {0.f, 0.f};
        #pragma unroll
        for (int mt = 0; mt < 2; ++mt) {
            const int j0 = jquad * 32 + mt * 16 + quad * 4;
            const float4 bv = *(const float4*)&b2[j0];
            const float4 wv = *(const float4*)&W3[j0];
            #pragma unroll
            for (int hp = 0; hp < 2; ++hp) {
                const v2f zb = hp ? (v2f){C[0][mt][2], C[0][mt][3]}
                                  : (v2f){C[0][mt][0], C[0][mt][1]};
                const v2f bb = hp ? (v2f){bv.z, bv.w} : (v2f){bv.x, bv.y};
                const v2f w3 = hp ? (v2f){wv.z, wv.w} : (v2f){wv.x, wv.y};
                const v2f tx = hp ? (v2f){C[1][mt][2], C[1][mt][3]}
                                  : (v2f){C[1][mt][0], C[1][mt][1]};
                const v2f ty = hp ? (v2f){C[2][mt][2], C[2][mt][3]}
                                  : (v2f){C[2][mt][0], C[2][mt][1]};
                const v2f cx = hp ? (v2f){C[3][mt][2], C[3][mt][3]}
                                  : (v2f){C[3][mt][0], C[3][mt][1]};
                const v2f cm = hp ? (v2f){C[4][mt][2], C[4][mt][3]}
                                  : (v2f){C[4][mt][0], C[4][mt][1]};
                const v2f cy = hp ? (v2f){C[5][mt][2], C[5][mt][3]}
                                  : (v2f){C[5][mt][0], C[5][mt][1]};
                v2f g1, g2;
                tanh_d2_p(zb + bb, g1, g2);
                const v2f gx = g2 * tx;
                axx = axx + w3 * (gx * tx + g1 * cx);
                axy = axy + w3 * (gx * ty + g1 * cm);
                ayy = ayy + w3 * ((g2 * ty) * ty + g1 * cy);
            }
        }
        float oxx = axx.x + axx.y, oxy = axy.x + axy.y, oyy = ayy.x + ayy.y;
        // reduce over quads (same p, disjoint j): 2-step butterfly
        oxx += __shfl_xor(oxx, 16); oxx += __shfl_xor(oxx, 32);
        oxy += __shfl_xor(oxy, 16); oxy += __shfl_xor(oxy, 32);
        oyy += __shfl_xor(oyy, 16); oyy += __shfl_xor(oyy, 32);
        // cross-wave (jquad) partials via sW-reuse
        float* sRed = (float*)sW;              // [3][4 jquad][32 p]
        if (quad == 0) {
            sRed[0 * 128 + jquad * 32 + pmy] = oxx;
            sRed[1 * 128 + jquad * 32 + pmy] = oxy;
            sRed[2 * 128 + jquad * 32 + pmy] = oyy;
        }
        __syncthreads();   // (5) partials visible
        if (tid < 96) {
            const int c = tid >> 5, p = tid & 31;
            float acc = 0.f;
            #pragma unroll
            for (int jq = 0; jq < 4; ++jq)
                acc += sRed[c * 128 + jq * 32 + p];
            out[c * N + pbase + p] = acc;
        }
    }
}

extern "C" void kernel_launch(void* const* d_in, const int* in_sizes, int n_in,
                              void* d_out, int out_size, void* d_ws, size_t ws_size,
                              hipStream_t stream) {
    const float* X  = (const float*)d_in[0];
    const float* W0 = (const float*)d_in[1];
    const float* b0 = (const float*)d_in[2];
    const float* W1 = (const float*)d_in[3];
    const float* b1 = (const float*)d_in[4];
    const float* W2 = (const float*)d_in[5];
    const float* b2 = (const float*)d_in[6];
    const float* W3 = (const float*)d_in[7];
    // d_in[8] = b3: constant offset, zero second derivative -> unused.

    const int N = in_sizes[0] / 2;               // 131072 = 4096 * P
    float* out = (float*)d_out;
    _Float16* ws = (_Float16*)d_ws;              // Wt[2][16][128][8] f16 = 64 KB

    hipLaunchKernelGGL(wt_convert, dim3(256), dim3(64), 0, stream, W1, W2, ws);

    hipLaunchKernelGGL(pinn_hess_mfma, dim3(N / P), dim3(NT), 0, stream,
                       X, W0, b0, ws, b1, b2, W3, out, N);
}

// Round 19
// 132.903 us; speedup vs baseline: 1.0047x; 1.0047x over previous
//
#include <hip/hip_runtime.h>

#define H   128
#define P   32             // points per block
#define NT  512            // 8 waves: wave = jquad*2 + phalf

typedef _Float16 v8h __attribute__((ext_vector_type(8)));
typedef __fp16   h2  __attribute__((ext_vector_type(2)));   // cvt_pkrtz return type
typedef float    v4f __attribute__((ext_vector_type(4)));
typedef float    v2f __attribute__((ext_vector_type(2)));   // -> VOP3P v_pk_*_f32

union PK4 { h2 h[4]; uint4 u; };       // 8 f16 = 16 B
union PK2 { h2 h[2]; uint2 u; };       // 4 f16 = 8 B

// State plane layout: [pl][p][k], 128 f16 per row, XOR-octet swizzle; returns
// f16 index of octet o of row p.
__device__ __forceinline__ int soct(int pl, int p, int o) {
    return ((pl * P + p) * 16 + (o ^ (p & 15))) << 3;
}

// Prepass (2nd dispatch is free — R10/R11 A/B): Wt in LDS physical order
// ws[l][oct][j][8], oct = k>>3. Main-kernel staging = pure linear memcpy.
__global__ void wt_convert(const float* __restrict__ W1,
                           const float* __restrict__ W2,
                           _Float16* __restrict__ ws) {
    const int t = blockIdx.x * 64 + threadIdx.x;   // 0..16383 (u32 units)
    const int l = t >> 13;
    const int r = t & 8191;
    const int oct = r >> 9;
    const int rem = r & 511;
    const int j  = rem >> 2;
    const int wp = rem & 3;
    const int k  = oct * 8 + 2 * wp;
    const float* __restrict__ W = l ? W2 : W1;
    const float a = W[k * H + j];
    const float b = W[(k + 1) * H + j];
    union { h2 h; unsigned u; } q;
    q.h = __builtin_amdgcn_cvt_pkrtz(a, b);
    ((unsigned*)ws)[t] = q.u;
}

// Packed-pair tanh + derivatives: exp/rcp scalar, fma chain packed (VOP3P).
__device__ __forceinline__ v2f tanh_d2_p(v2f z, v2f& g1, v2f& g2) {
    v2f r;
    r.x = __builtin_amdgcn_rcpf(__expf(2.f * z.x) + 1.f);
    r.y = __builtin_amdgcn_rcpf(__expf(2.f * z.y) + 1.f);
    const v2f a = -2.f * r + 1.f;                  // e=inf -> r=0 -> a=1
    g1 = 1.f - a * a;
    g2 = -2.f * (a * g1);
    return a;
}

// FINAL (= R17, measured best 71.3-71.6us kernel). Structure:
//  - forward-mode 2nd-order propagation: 6 state planes {h,tx,ty,sxx,sxy,syy}
//  - per layer one 6Px128 f16 MFMA GEMM vs W^T; A = Wt (m=j, LDS, staged once
//    per layer via linear memcpy of the pre-swizzled prepass output),
//    B = state (n=p, LDS, XOR-octet swizzle); C row j = quad*4+r, col p = l15
//    -> tanh chain rule entirely in registers, b64 vector state writeback
//  - packed-fp32 (VOP3P) elementwise; fast tanh via v_exp+v_rcp
//  - 5 barriers/block; (512,4) reg cap (52 VGPR, no spill); 2 blocks/CU.
// Plateau evidence: R16 reg-prefetch neutral, R17 packed math cut VALU 20%
// with no dur change, R18 DMA staging -3% -> multi-pipe floor (MFMA 32%,
// VALU 48%, LDS ~65%), phase-serialization residual at 16 waves/CU.
__global__ __launch_bounds__(NT, 4)
void pinn_hess_mfma(const float* __restrict__ X,
                    const float* __restrict__ W0, const float* __restrict__ b0,
                    const _Float16* __restrict__ Wt,
                    const float* __restrict__ b1, const float* __restrict__ b2,
                    const float* __restrict__ W3,
                    float* __restrict__ out, int N)
{
    __shared__ _Float16 sS[6 * P * H];        // 49152 B, swizzled state planes
    __shared__ _Float16 sW[16 * H * 8];       // 32768 B, one full W layer (oct-planes)

    const int tid   = threadIdx.x;
    const int wave  = tid >> 6;               // 0..7
    const int phalf = wave & 1;               // p-half: cols phalf*16..+16
    const int jquad = wave >> 1;              // j range jquad*32..+32
    const int lane  = tid & 63;
    const int quad  = lane >> 4;
    const int l15   = lane & 15;
    const int pbase = blockIdx.x * P;
    const int pmy   = phalf * 16 + l15;       // this lane's point row (GEMM n)

    // ---------------- layer 0 (input dim 2, analytic); 512 tasks = 1/thread --
    {
        const int p = tid >> 4, o = tid & 15;
        const float x = X[2 * (pbase + p)];
        const float y = X[2 * (pbase + p) + 1];
        float wxv[8], wyv[8], bv[8];
        *(float4*)&wxv[0] = *(const float4*)&W0[o * 8];
        *(float4*)&wxv[4] = *(const float4*)&W0[o * 8 + 4];
        *(float4*)&wyv[0] = *(const float4*)&W0[H + o * 8];
        *(float4*)&wyv[4] = *(const float4*)&W0[H + o * 8 + 4];
        *(float4*)&bv[0]  = *(const float4*)&b0[o * 8];
        *(float4*)&bv[4]  = *(const float4*)&b0[o * 8 + 4];
        PK4 q[6];
        #pragma unroll
        for (int hp = 0; hp < 4; ++hp) {       // j-pairs, packed math
            const v2f wx = {wxv[2*hp], wxv[2*hp+1]};
            const v2f wy = {wyv[2*hp], wyv[2*hp+1]};
            const v2f bb = {bv[2*hp],  bv[2*hp+1]};
            v2f g1, g2;
            const v2f a = tanh_d2_p(x * wx + y * wy + bb, g1, g2);
            const v2f gx = g2 * wx;
            const v2f r0 = a,        r1 = g1 * wx,  r2 = g1 * wy;
            const v2f r3 = gx * wx,  r4 = gx * wy,  r5 = (g2 * wy) * wy;
            q[0].h[hp] = __builtin_amdgcn_cvt_pkrtz(r0.x, r0.y);
            q[1].h[hp] = __builtin_amdgcn_cvt_pkrtz(r1.x, r1.y);
            q[2].h[hp] = __builtin_amdgcn_cvt_pkrtz(r2.x, r2.y);
            q[3].h[hp] = __builtin_amdgcn_cvt_pkrtz(r3.x, r3.y);
            q[4].h[hp] = __builtin_amdgcn_cvt_pkrtz(r4.x, r4.y);
            q[5].h[hp] = __builtin_amdgcn_cvt_pkrtz(r5.x, r5.y);
        }
        #pragma unroll
        for (int pl = 0; pl < 6; ++pl)
            *(uint4*)&sS[soct(pl, p, o)] = q[pl].u;
    }

    // ---------------- hidden layers ----------------
    for (int layer = 0; layer < 2; ++layer) {
        // stage whole layer: linear memcpy, 4 b128 per thread, both sides coalesced
        {
            const v8h* src = (const v8h*)(Wt + layer * 16 * H * 8);
            v8h*       dst = (v8h*)sW;
            #pragma unroll
            for (int i = 0; i < 4; ++i)
                dst[tid + i * NT] = src[tid + i * NT];
        }
        __syncthreads();   // (1)/(3): sW + sS writes visible

        v4f C[6][2];
        #pragma unroll
        for (int pl = 0; pl < 6; ++pl) { C[pl][0] = (v4f){0,0,0,0}; C[pl][1] = (v4f){0,0,0,0}; }

        #pragma unroll
        for (int kc = 0; kc < 4; ++kc) {
            const int oct = kc * 4 + quad;
            const v8h A0 = *(const v8h*)&sW[(oct * H + jquad * 32 + l15)      * 8];
            const v8h A1 = *(const v8h*)&sW[(oct * H + jquad * 32 + 16 + l15) * 8];
            #pragma unroll
            for (int pl = 0; pl < 6; ++pl) {
                const v8h B = *(const v8h*)&sS[soct(pl, pmy, oct)];
                C[pl][0] = __builtin_amdgcn_mfma_f32_16x16x32_f16(A0, B, C[pl][0], 0, 0, 0);
                C[pl][1] = __builtin_amdgcn_mfma_f32_16x16x32_f16(A1, B, C[pl][1], 0, 0, 0);
            }
        }
        __syncthreads();   // (2)/(4): all K-loop reads of sS + sW done

        if (layer == 0) {
            // packed in-register tanh chain rule; b64 vector writeback
            #pragma unroll
            for (int mt = 0; mt < 2; ++mt) {
                const int j0 = jquad * 32 + mt * 16 + quad * 4;
                const float4 bv = *(const float4*)&b1[j0];
                PK2 q[6];
                #pragma unroll
                for (int hp = 0; hp < 2; ++hp) {   // r-pairs (0,1) and (2,3)
                    const v2f zb = hp ? (v2f){C[0][mt][2], C[0][mt][3]}
                                      : (v2f){C[0][mt][0], C[0][mt][1]};
                    const v2f bb = hp ? (v2f){bv.z, bv.w} : (v2f){bv.x, bv.y};
                    const v2f tx = hp ? (v2f){C[1][mt][2], C[1][mt][3]}
                                      : (v2f){C[1][mt][0], C[1][mt][1]};
                    const v2f ty = hp ? (v2f){C[2][mt][2], C[2][mt][3]}
                                      : (v2f){C[2][mt][0], C[2][mt][1]};
                    const v2f cx = hp ? (v2f){C[3][mt][2], C[3][mt][3]}
                                      : (v2f){C[3][mt][0], C[3][mt][1]};
                    const v2f cm = hp ? (v2f){C[4][mt][2], C[4][mt][3]}
                                      : (v2f){C[4][mt][0], C[4][mt][1]};
                    const v2f cy = hp ? (v2f){C[5][mt][2], C[5][mt][3]}
                                      : (v2f){C[5][mt][0], C[5][mt][1]};
                    v2f g1, g2;
                    const v2f a  = tanh_d2_p(zb + bb, g1, g2);
                    const v2f gx = g2 * tx;
                    const v2f s0 = a,        s1 = g1 * tx,          s2 = g1 * ty;
                    const v2f s3 = gx * tx + g1 * cx;
                    const v2f s4 = gx * ty + g1 * cm;
                    const v2f s5 = (g2 * ty) * ty + g1 * cy;
                    q[0].h[hp] = __builtin_amdgcn_cvt_pkrtz(s0.x, s0.y);
                    q[1].h[hp] = __builtin_amdgcn_cvt_pkrtz(s1.x, s1.y);
                    q[2].h[hp] = __builtin_amdgcn_cvt_pkrtz(s2.x, s2.y);
                    q[3].h[hp] = __builtin_amdgcn_cvt_pkrtz(s3.x, s3.y);
                    q[4].h[hp] = __builtin_amdgcn_cvt_pkrtz(s4.x, s4.y);
                    q[5].h[hp] = __builtin_amdgcn_cvt_pkrtz(s5.x, s5.y);
                }
                const int ob = j0 >> 3;            // octet of j0
                const int ho = (quad & 1) * 4;     // half-offset within octet
                #pragma unroll
                for (int pl = 0; pl < 6; ++pl)
                    *(uint2*)&sS[soct(pl, pmy, ob) + ho] = q[pl].u;
            }
        } else {
            // final combine + W3 dot, packed; reduce j over quads then jquads
            v2f axx = {0.f, 0.f}, axy = {0.f, 0.f}, ayy = {0.f, 0.f};
            #pragma unroll
            for (int mt = 0; mt < 2; ++mt) {
                const int j0 = jquad * 32 + mt * 16 + quad * 4;
                const float4 bv = *(const float4*)&b2[j0];
                const float4 wv = *(const float4*)&W3[j0];
                #pragma unroll
                for (int hp = 0; hp < 2; ++hp) {
                    const v2f zb = hp ? (v2f){C[0][mt][2], C[0][mt][3]}
                                      : (v2f){C[0][mt][0], C[0][mt][1]};
                    const v2f bb = hp ? (v2f){bv.z, bv.w} : (v2f){bv.x, bv.y};
                    const v2f w3 = hp ? (v2f){wv.z, wv.w} : (v2f){wv.x, wv.y};
                    const v2f tx = hp ? (v2f){C[1][mt][2], C[1][mt][3]}
                                      : (v2f){C[1][mt][0], C[1][mt][1]};
                    const v2f ty = hp ? (v2f){C[2][mt][2], C[2][mt][3]}
                                      : (v2f){C[2][mt][0], C[2][mt][1]};
                    const v2f cx = hp ? (v2f){C[3][mt][2], C[3][mt][3]}
                                      : (v2f){C[3][mt][0], C[3][mt][1]};
                    const v2f cm = hp ? (v2f){C[4][mt][2], C[4][mt][3]}
                                      : (v2f){C[4][mt][0], C[4][mt][1]};
                    const v2f cy = hp ? (v2f){C[5][mt][2], C[5][mt][3]}
                                      : (v2f){C[5][mt][0], C[5][mt][1]};
                    v2f g1, g2;
                    tanh_d2_p(zb + bb, g1, g2);
                    const v2f gx = g2 * tx;
                    axx = axx + w3 * (gx * tx + g1 * cx);
                    axy = axy + w3 * (gx * ty + g1 * cm);
                    ayy = ayy + w3 * ((g2 * ty) * ty + g1 * cy);
                }
            }
            float oxx = axx.x + axx.y, oxy = axy.x + axy.y, oyy = ayy.x + ayy.y;
            // reduce over quads (same p, disjoint j): 2-step butterfly
            oxx += __shfl_xor(oxx, 16); oxx += __shfl_xor(oxx, 32);
            oxy += __shfl_xor(oxy, 16); oxy += __shfl_xor(oxy, 32);
            oyy += __shfl_xor(oyy, 16); oyy += __shfl_xor(oyy, 32);
            // cross-wave (jquad) partials via sW-reuse
            float* sRed = (float*)sW;              // [3][4 jquad][32 p]
            if (quad == 0) {
                sRed[0 * 128 + jquad * 32 + pmy] = oxx;
                sRed[1 * 128 + jquad * 32 + pmy] = oxy;
                sRed[2 * 128 + jquad * 32 + pmy] = oyy;
            }
            __syncthreads();   // (5) partials visible
            if (tid < 96) {
                const int c = tid >> 5, p = tid & 31;
                float acc = 0.f;
                #pragma unroll
                for (int jq = 0; jq < 4; ++jq)
                    acc += sRed[c * 128 + jq * 32 + p];
                out[c * N + pbase + p] = acc;
            }
        }
    }
}

extern "C" void kernel_launch(void* const* d_in, const int* in_sizes, int n_in,
                              void* d_out, int out_size, void* d_ws, size_t ws_size,
                              hipStream_t stream) {
    const float* X  = (const float*)d_in[0];
    const float* W0 = (const float*)d_in[1];
    const float* b0 = (const float*)d_in[2];
    const float* W1 = (const float*)d_in[3];
    const float* b1 = (const float*)d_in[4];
    const float* W2 = (const float*)d_in[5];
    const float* b2 = (const float*)d_in[6];
    const float* W3 = (const float*)d_in[7];
    // d_in[8] = b3: constant offset, zero second derivative -> unused.

    const int N = in_sizes[0] / 2;               // 131072 = 4096 * P
    float* out = (float*)d_out;
    _Float16* ws = (_Float16*)d_ws;              // Wt[2][16][128][8] f16 = 64 KB

    hipLaunchKernelGGL(wt_convert, dim3(256), dim3(64), 0, stream, W1, W2, ws);

    hipLaunchKernelGGL(pinn_hess_mfma, dim3(N / P), dim3(NT), 0, stream,
                       X, W0, b0, ws, b1, b2, W3, out, N);
}